// Round 13
// baseline (244.277 us; speedup 1.0000x reference)
//
#include <hip/hip_runtime.h>
#include <hip/hip_bf16.h>

#define N_NODES 50000
#define N_EDGES 800000
#define ET_EDGES (N_EDGES + N_NODES)   // 850000
#define NFEAT 128
#define NCLASS 64
#define NHEADS 8
#define HIDDEN 32
#define NAB 64            // nb row: a(32) | b(32) fp8, b has b1 folded in
#define KAGG 1024         // 8 heads * 128 feat
#define NSLOT 64          // denom slot hashing
typedef unsigned short u16;
typedef unsigned int u32;
typedef unsigned char u8;

typedef __attribute__((ext_vector_type(8))) short bf16x8;
typedef __attribute__((ext_vector_type(4))) float f32x4;
typedef __attribute__((ext_vector_type(2))) float f32x2;
typedef __attribute__((ext_vector_type(4))) unsigned int u32x4;   // native vec for nt stores

static __device__ __forceinline__ u16 f2bf(float f) {
    u32 u = __float_as_uint(f);
    return (u16)((u + 0x7fffu + ((u >> 16) & 1u)) >> 16);  // RNE
}
static __device__ __forceinline__ u32 pack2bf(float lo, float hi) {
    return (u32)f2bf(lo) | ((u32)f2bf(hi) << 16);
}
static __device__ __forceinline__ float bfl(u32 u) { return __uint_as_float(u << 16); }
static __device__ __forceinline__ float bfh(u32 u) { return __uint_as_float(u & 0xffff0000u); }
static __device__ __forceinline__ u8 f2fp8(float f) {
    return (u8)(__builtin_amdgcn_cvt_pk_fp8_f32(f, 0.f, 0, false) & 0xff);
}

// ---- merged prep: WpT pack | pwT pack | deg histogram + per-edge rank capture ----
__global__ __launch_bounds__(256) void k_prep(const float* __restrict__ w1,
                                              const float* __restrict__ proj_w,
                                              const int* __restrict__ ei,
                                              u16* __restrict__ WpT,
                                              u16* __restrict__ pwT,
                                              int* __restrict__ deg,
                                              int* __restrict__ rank) {
    int b = blockIdx.x;
    if (b < 32) {                                   // WpT [64][128] bf16
        int idx = b * 256 + threadIdx.x;
        int o = idx / NFEAT, k = idx % NFEAT;
        float v = (o < HIDDEN) ? w1[k * HIDDEN + o]
                               : w1[(NFEAT + k) * HIDDEN + (o - HIDDEN)];
        WpT[idx] = f2bf(v);
    } else if (b < 32 + 256) {                      // pwT [64][1024] bf16
        int idx = (b - 32) * 256 + threadIdx.x;
        int c = idx >> 10, k = idx & (KAGG - 1);
        pwT[idx] = f2bf(proj_w[(size_t)k * NCLASS + c]);
    } else {                                        // deg histogram; rank = slot within node
        int e = (b - 288) * 256 + threadIdx.x;
        if (e < N_EDGES) rank[e] = atomicAdd(&deg[ei[N_EDGES + e]], 1);
    }
}

// ---- GEMM1: nb[N][64] fp8 = x[N][128] @ WpT^T (+b1 on b-cols); write-through xb bf16 ----
#define ROWP 136
__global__ __launch_bounds__(256) void k_gemm(const float* __restrict__ x,
                                              const u16* __restrict__ WpT,
                                              const float* __restrict__ b1v,
                                              u8* __restrict__ nb,
                                              u16* __restrict__ xb) {
    __shared__ __align__(16) u16 As[128 * ROWP];
    __shared__ __align__(16) u16 Bs[64 * ROWP];
    int tid = threadIdx.x;
    int m0 = blockIdx.x * 128;
    int wv = tid >> 6, l = tid & 63, lr = l & 15, lg = l >> 4;

#pragma unroll
    for (int p = 0; p < 8; ++p) {
        int idx = tid + p * 256;
        int row = idx >> 4, fo = idx & 15;
        int gm = m0 + row;
        float4 f0 = make_float4(0.f,0.f,0.f,0.f), f1 = f0;
        if (gm < N_NODES) {
            const float* xp = x + (size_t)gm * NFEAT + fo * 8;
            f0 = *(const float4*)xp;
            f1 = *(const float4*)(xp + 4);
        }
        uint4 v;
        v.x = pack2bf(f0.x, f0.y); v.y = pack2bf(f0.z, f0.w);
        v.z = pack2bf(f1.x, f1.y); v.w = pack2bf(f1.z, f1.w);
        *(uint4*)&As[row * ROWP + fo * 8] = v;
        if (gm < N_NODES) *(uint4*)(xb + (size_t)gm * NFEAT + fo * 8) = v;
    }
#pragma unroll
    for (int p = 0; p < 4; ++p) {
        int idx = tid + p * 256;
        int col = idx >> 4, fo = idx & 15;
        *(uint4*)&Bs[col * ROWP + fo * 8] = *(const uint4*)(WpT + (size_t)col * NFEAT + fo * 8);
    }
    __syncthreads();
    union FR { uint4 q; bf16x8 v; };
    f32x4 acc[2][4];
#pragma unroll
    for (int fr = 0; fr < 2; ++fr)
#pragma unroll
        for (int fc = 0; fc < 4; ++fc) acc[fr][fc] = (f32x4){0.f, 0.f, 0.f, 0.f};
#pragma unroll
    for (int ks = 0; ks < 4; ++ks) {
        int k0 = ks * 32;
        FR a0, a1, b0, b1, b2, b3;
        a0.q = *(const uint4*)&As[(wv * 32 + 0  + lr) * ROWP + k0 + 8 * lg];
        a1.q = *(const uint4*)&As[(wv * 32 + 16 + lr) * ROWP + k0 + 8 * lg];
        b0.q = *(const uint4*)&Bs[(0  + lr) * ROWP + k0 + 8 * lg];
        b1.q = *(const uint4*)&Bs[(16 + lr) * ROWP + k0 + 8 * lg];
        b2.q = *(const uint4*)&Bs[(32 + lr) * ROWP + k0 + 8 * lg];
        b3.q = *(const uint4*)&Bs[(48 + lr) * ROWP + k0 + 8 * lg];
        acc[0][0] = __builtin_amdgcn_mfma_f32_16x16x32_bf16(a0.v, b0.v, acc[0][0], 0, 0, 0);
        acc[0][1] = __builtin_amdgcn_mfma_f32_16x16x32_bf16(a0.v, b1.v, acc[0][1], 0, 0, 0);
        acc[0][2] = __builtin_amdgcn_mfma_f32_16x16x32_bf16(a0.v, b2.v, acc[0][2], 0, 0, 0);
        acc[0][3] = __builtin_amdgcn_mfma_f32_16x16x32_bf16(a0.v, b3.v, acc[0][3], 0, 0, 0);
        acc[1][0] = __builtin_amdgcn_mfma_f32_16x16x32_bf16(a1.v, b0.v, acc[1][0], 0, 0, 0);
        acc[1][1] = __builtin_amdgcn_mfma_f32_16x16x32_bf16(a1.v, b1.v, acc[1][1], 0, 0, 0);
        acc[1][2] = __builtin_amdgcn_mfma_f32_16x16x32_bf16(a1.v, b2.v, acc[1][2], 0, 0, 0);
        acc[1][3] = __builtin_amdgcn_mfma_f32_16x16x32_bf16(a1.v, b3.v, acc[1][3], 0, 0, 0);
    }
    // D[row = wv*32+fr*16+4*lg+r][col = fc*16+lr] ; b1 folded into cols 32..63; fp8 store
    float badd[4];
    badd[0] = 0.f; badd[1] = 0.f; badd[2] = b1v[lr]; badd[3] = b1v[16 + lr];
#pragma unroll
    for (int fr = 0; fr < 2; ++fr)
#pragma unroll
        for (int fc = 0; fc < 4; ++fc)
#pragma unroll
            for (int r = 0; r < 4; ++r) {
                int gm = m0 + wv * 32 + fr * 16 + 4 * lg + r;
                if (gm < N_NODES)
                    nb[(size_t)gm * NAB + fc * 16 + lr] = f2fp8(acc[fr][fc][r] + badd[fc]);
            }
}

// ---- scan (3 kernels); scan1 adds +1 per node for the self-loop ----
__global__ __launch_bounds__(1024) void k_scan1(const int* __restrict__ deg,
                                                int* __restrict__ rowptr,
                                                int* __restrict__ bsum) {
    __shared__ int sd[1024];
    int tid = threadIdx.x;
    int i = blockIdx.x * 1024 + tid;
    int v = (i < N_NODES) ? deg[i] + 1 : 0;
    sd[tid] = v;
    __syncthreads();
    for (int off = 1; off < 1024; off <<= 1) {
        int t = (tid >= off) ? sd[tid - off] : 0;
        __syncthreads();
        sd[tid] += t;
        __syncthreads();
    }
    if (i < N_NODES) rowptr[i] = sd[tid] - v;
    if (tid == 1023) bsum[blockIdx.x] = sd[1023];
}
#define NBLK_SCAN 49
__global__ __launch_bounds__(64) void k_scan2(const int* __restrict__ bsum,
                                              int* __restrict__ boff,
                                              int* __restrict__ rowptr) {
    int l = threadIdx.x;
    int orig = (l < NBLK_SCAN) ? bsum[l] : 0;
    int v = orig;
    for (int off = 1; off < 64; off <<= 1) {
        int t = __shfl_up(v, off);
        if (l >= off) v += t;
    }
    if (l < NBLK_SCAN) boff[l] = v - orig;
    if (l == 63) rowptr[N_NODES] = v;
}
__global__ __launch_bounds__(256) void k_scan3(int* __restrict__ rowptr,
                                               const int* __restrict__ boff) {
    int i = blockIdx.x * 256 + threadIdx.x;
    if (i >= N_NODES) return;
    rowptr[i] += boff[i >> 10];
}

// ---- fused per-edge MLP + gate + exp + CSR scatter; NO atomics (rank-based slot) ----
__global__ __launch_bounds__(256) void k_edges(const u8* __restrict__ nb,
                                               const int* __restrict__ ei,
                                               const int* __restrict__ rank,
                                               const int* __restrict__ rowptr,
                                               const float* __restrict__ eww,
                                               const float* __restrict__ w2,
                                               const float* __restrict__ b2v,
                                               u32* __restrict__ esb,
                                               float* __restrict__ dslot) {
    int e = blockIdx.x * 256 + threadIdx.x;
    bool valid = e < ET_EDGES;
    int s = 0, d = 0, pos = 0;
    if (valid) {
        if (e < N_EDGES) {
            s = ei[e]; d = ei[N_EDGES + e];
            pos = rowptr[d] + rank[e];          // unique slot, no RMW
        } else {
            s = d = e - N_EDGES;
            pos = rowptr[d + 1] - 1;            // self-loop takes the reserved last slot
        }
    }
    // eww loads depend only on e: issue before anything needs them
    int ee = valid ? e : 0;
    float ew[NHEADS];
#pragma unroll
    for (int t = 0; t < NHEADS; ++t) ew[t] = eww[(size_t)t * ET_EDGES + ee];

    const uint4* rp = (const uint4*)(nb + (size_t)s * NAB);   // a = bytes 0..31
    const uint4* rq = (const uint4*)(nb + (size_t)d * NAB);   // b = bytes 32..63
    uint4 Au = rp[0], Av = rp[1];
    uint4 Bu = rq[2], Bv = rq[3];

    float h[HIDDEN];
#define DEC8(au, bu, base) { \
        f32x2 al = __builtin_amdgcn_cvt_pk_f32_fp8((int)(au), false); \
        f32x2 ah = __builtin_amdgcn_cvt_pk_f32_fp8((int)(au), true);  \
        f32x2 bl = __builtin_amdgcn_cvt_pk_f32_fp8((int)(bu), false); \
        f32x2 bh = __builtin_amdgcn_cvt_pk_f32_fp8((int)(bu), true);  \
        h[base+0] = fmaxf(al.x + bl.x, 0.f); h[base+1] = fmaxf(al.y + bl.y, 0.f); \
        h[base+2] = fmaxf(ah.x + bh.x, 0.f); h[base+3] = fmaxf(ah.y + bh.y, 0.f); }
    DEC8(Au.x, Bu.x, 0)  DEC8(Au.y, Bu.y, 4)  DEC8(Au.z, Bu.z, 8)  DEC8(Au.w, Bu.w, 12)
    DEC8(Av.x, Bv.x, 16) DEC8(Av.y, Bv.y, 20) DEC8(Av.z, Bv.z, 24) DEC8(Av.w, Bv.w, 28)
#undef DEC8

    float z[NHEADS];
#pragma unroll
    for (int t = 0; t < NHEADS; ++t) z[t] = 0.f;
#pragma unroll
    for (int j = 0; j < HIDDEN; ++j)
#pragma unroll
        for (int t = 0; t < NHEADS; ++t) z[t] = fmaf(h[j], w2[j * NHEADS + t], z[t]);

    float pe[NHEADS];
#pragma unroll
    for (int t = 0; t < NHEADS; ++t) {
        float dyn = 1.f / (1.f + __expf(-(z[t] + b2v[t])));
        float tw  = ew[t] * dyn;
        tw = fmaxf(tw, 0.01f * tw);                 // leaky_relu
        pe[t] = valid ? __expf(tw) : 0.f;
    }
    if (valid) {
        u32x4 q0, q1;
        q0.x = pack2bf(pe[0], pe[1]); q0.y = pack2bf(pe[2], pe[3]);
        q0.z = pack2bf(pe[4], pe[5]); q0.w = pack2bf(pe[6], pe[7]);
        q1.x = (u32)s; q1.y = 0u; q1.z = 0u; q1.w = 0u;
        u32x4* dst = (u32x4*)(esb + 8 * (size_t)pos);   // one 32B record: single line touch
        __builtin_nontemporal_store(q0, dst);           // nt: no write-allocate (stream)
        __builtin_nontemporal_store(q1, dst + 1);
    }
    __shared__ float blk[NHEADS];
    if (threadIdx.x < NHEADS) blk[threadIdx.x] = 0.f;
    __syncthreads();
    int lane = threadIdx.x & 63;
#pragma unroll
    for (int t = 0; t < NHEADS; ++t) {
        float v = pe[t];
        for (int off = 32; off > 0; off >>= 1) v += __shfl_xor(v, off);
        if (lane == 0) atomicAdd(&blk[t], v);
    }
    __syncthreads();
    if (threadIdx.x < NHEADS)
        atomicAdd(&dslot[(blockIdx.x & (NSLOT - 1)) * NHEADS + threadIdx.x], blk[threadIdx.x]);
}

// ---- aggregate: SGPR record loads + v_pk_fma_f32; bf16 aggx out (nt stores) ----
__global__ __launch_bounds__(256) void k_agg(const u16* __restrict__ xb,
                                             const u32* __restrict__ esb,
                                             const int* __restrict__ rowptr,
                                             const float* __restrict__ dslot,
                                             u16* __restrict__ aggx) {
    int lane = threadIdx.x & 63;
    int n = __builtin_amdgcn_readfirstlane(blockIdx.x * 4 + (threadIdx.x >> 6));
    if (n >= N_NODES) return;
    f32x2 acc[8];
#pragma unroll
    for (int h = 0; h < 8; ++h) acc[h] = (f32x2){0.f, 0.f};
    int beg = __builtin_amdgcn_readfirstlane(rowptr[n]);
    int end = __builtin_amdgcn_readfirstlane(rowptr[n + 1]);
    const u32* rec = esb;                      // uniform base; idx uniform -> s_load
    const u16* xrow = xb + 2 * lane;

#define WACC(w0u, w1u, w2u, w3u, xv) { \
        acc[0] = __builtin_elementwise_fma((f32x2){bfl(w0u), bfl(w0u)}, xv, acc[0]); \
        acc[1] = __builtin_elementwise_fma((f32x2){bfh(w0u), bfh(w0u)}, xv, acc[1]); \
        acc[2] = __builtin_elementwise_fma((f32x2){bfl(w1u), bfl(w1u)}, xv, acc[2]); \
        acc[3] = __builtin_elementwise_fma((f32x2){bfh(w1u), bfh(w1u)}, xv, acc[3]); \
        acc[4] = __builtin_elementwise_fma((f32x2){bfl(w2u), bfl(w2u)}, xv, acc[4]); \
        acc[5] = __builtin_elementwise_fma((f32x2){bfh(w2u), bfh(w2u)}, xv, acc[5]); \
        acc[6] = __builtin_elementwise_fma((f32x2){bfl(w3u), bfl(w3u)}, xv, acc[6]); \
        acc[7] = __builtin_elementwise_fma((f32x2){bfh(w3u), bfh(w3u)}, xv, acc[7]); }

    int idx = beg;
    for (; idx + 2 <= end; idx += 2) {
        size_t r = (size_t)idx * 8;            // u32 index of record
        u32 a0 = rec[r + 0], a1 = rec[r + 1], a2 = rec[r + 2], a3 = rec[r + 3];
        int  s0 = (int)rec[r + 4];
        u32 b0 = rec[r + 8], b1 = rec[r + 9], b2 = rec[r + 10], b3 = rec[r + 11];
        int  s1 = (int)rec[r + 12];
        u32 xu0 = *(const u32*)(xrow + (size_t)s0 * NFEAT);
        u32 xu1 = *(const u32*)(xrow + (size_t)s1 * NFEAT);
        f32x2 xv0 = {bfl(xu0), bfh(xu0)};
        f32x2 xv1 = {bfl(xu1), bfh(xu1)};
        WACC(a0, a1, a2, a3, xv0)
        WACC(b0, b1, b2, b3, xv1)
    }
    if (idx < end) {
        size_t r = (size_t)idx * 8;
        u32 a0 = rec[r + 0], a1 = rec[r + 1], a2 = rec[r + 2], a3 = rec[r + 3];
        int  s0 = (int)rec[r + 4];
        u32 xu0 = *(const u32*)(xrow + (size_t)s0 * NFEAT);
        f32x2 xv0 = {bfl(xu0), bfh(xu0)};
        WACC(a0, a1, a2, a3, xv0)
    }
#undef WACC
    // epilogue: wave-parallel denom reduce over 64 slots (lane = slot); regs free here
    float4 da = *(const float4*)(dslot + lane * NHEADS);
    float4 db = *(const float4*)(dslot + lane * NHEADS + 4);
#pragma unroll
    for (int off = 32; off > 0; off >>= 1) {
        da.x += __shfl_xor(da.x, off); da.y += __shfl_xor(da.y, off);
        da.z += __shfl_xor(da.z, off); da.w += __shfl_xor(da.w, off);
        db.x += __shfl_xor(db.x, off); db.y += __shfl_xor(db.y, off);
        db.z += __shfl_xor(db.z, off); db.w += __shfl_xor(db.w, off);
    }
    u16* dst = aggx + (size_t)n * KAGG + 2 * lane;
    __builtin_nontemporal_store(pack2bf(acc[0][0] / da.x, acc[0][1] / da.x), (u32*)(dst + 0 * NFEAT));
    __builtin_nontemporal_store(pack2bf(acc[1][0] / da.y, acc[1][1] / da.y), (u32*)(dst + 1 * NFEAT));
    __builtin_nontemporal_store(pack2bf(acc[2][0] / da.z, acc[2][1] / da.z), (u32*)(dst + 2 * NFEAT));
    __builtin_nontemporal_store(pack2bf(acc[3][0] / da.w, acc[3][1] / da.w), (u32*)(dst + 3 * NFEAT));
    __builtin_nontemporal_store(pack2bf(acc[4][0] / db.x, acc[4][1] / db.x), (u32*)(dst + 4 * NFEAT));
    __builtin_nontemporal_store(pack2bf(acc[5][0] / db.y, acc[5][1] / db.y), (u32*)(dst + 5 * NFEAT));
    __builtin_nontemporal_store(pack2bf(acc[6][0] / db.z, acc[6][1] / db.z), (u32*)(dst + 6 * NFEAT));
    __builtin_nontemporal_store(pack2bf(acc[7][0] / db.w, acc[7][1] / db.w), (u32*)(dst + 7 * NFEAT));
}

// ---- GEMM2 + bias + LayerNorm: out[N][64] = LN(aggx[N][1024] @ pwT^T + proj_b) ----
__global__ __launch_bounds__(256) void k_out(const u16* __restrict__ aggx,
                                             const u16* __restrict__ pwT,
                                             const float* __restrict__ proj_b,
                                             const float* __restrict__ ln_g,
                                             const float* __restrict__ ln_b,
                                             float* __restrict__ out) {
    __shared__ __align__(16) u16 As[128 * ROWP];
    __shared__ __align__(16) u16 Bs[64 * ROWP];
    int tid = threadIdx.x;
    int m0 = blockIdx.x * 128;
    int wv = tid >> 6, l = tid & 63, lr = l & 15, lg = l >> 4;
    union FR { uint4 q; bf16x8 v; };
    f32x4 acc[2][4];
#pragma unroll
    for (int fr = 0; fr < 2; ++fr)
#pragma unroll
        for (int fc = 0; fc < 4; ++fc) acc[fr][fc] = (f32x4){0.f, 0.f, 0.f, 0.f};

    for (int kt = 0; kt < 8; ++kt) {
        int kb = kt * 128;
        __syncthreads();
#pragma unroll
        for (int p = 0; p < 8; ++p) {
            int idx = tid + p * 256;
            int row = idx >> 4, fo = idx & 15;
            int gm = m0 + row;
            uint4 v = make_uint4(0u, 0u, 0u, 0u);
            if (gm < N_NODES) v = *(const uint4*)(aggx + (size_t)gm * KAGG + kb + fo * 8);
            *(uint4*)&As[row * ROWP + fo * 8] = v;
        }
#pragma unroll
        for (int p = 0; p < 4; ++p) {
            int idx = tid + p * 256;
            int col = idx >> 4, fo = idx & 15;
            *(uint4*)&Bs[col * ROWP + fo * 8] =
                *(const uint4*)(pwT + (size_t)col * KAGG + kb + fo * 8);
        }
        __syncthreads();
#pragma unroll
        for (int ks = 0; ks < 4; ++ks) {
            int k0 = ks * 32;
            FR a0, a1, b0, b1, b2, b3;
            a0.q = *(const uint4*)&As[(wv * 32 + 0  + lr) * ROWP + k0 + 8 * lg];
            a1.q = *(const uint4*)&As[(wv * 32 + 16 + lr) * ROWP + k0 + 8 * lg];
            b0.q = *(const uint4*)&Bs[(0  + lr) * ROWP + k0 + 8 * lg];
            b1.q = *(const uint4*)&Bs[(16 + lr) * ROWP + k0 + 8 * lg];
            b2.q = *(const uint4*)&Bs[(32 + lr) * ROWP + k0 + 8 * lg];
            b3.q = *(const uint4*)&Bs[(48 + lr) * ROWP + k0 + 8 * lg];
            acc[0][0] = __builtin_amdgcn_mfma_f32_16x16x32_bf16(a0.v, b0.v, acc[0][0], 0, 0, 0);
            acc[0][1] = __builtin_amdgcn_mfma_f32_16x16x32_bf16(a0.v, b1.v, acc[0][1], 0, 0, 0);
            acc[0][2] = __builtin_amdgcn_mfma_f32_16x16x32_bf16(a0.v, b2.v, acc[0][2], 0, 0, 0);
            acc[0][3] = __builtin_amdgcn_mfma_f32_16x16x32_bf16(a0.v, b3.v, acc[0][3], 0, 0, 0);
            acc[1][0] = __builtin_amdgcn_mfma_f32_16x16x32_bf16(a1.v, b0.v, acc[1][0], 0, 0, 0);
            acc[1][1] = __builtin_amdgcn_mfma_f32_16x16x32_bf16(a1.v, b1.v, acc[1][1], 0, 0, 0);
            acc[1][2] = __builtin_amdgcn_mfma_f32_16x16x32_bf16(a1.v, b2.v, acc[1][2], 0, 0, 0);
            acc[1][3] = __builtin_amdgcn_mfma_f32_16x16x32_bf16(a1.v, b3.v, acc[1][3], 0, 0, 0);
        }
    }
    float pb4[4], g4[4], b4[4];
#pragma unroll
    for (int fc = 0; fc < 4; ++fc) {
        pb4[fc] = proj_b[fc * 16 + lr];
        g4[fc]  = ln_g[fc * 16 + lr];
        b4[fc]  = ln_b[fc * 16 + lr];
    }
#pragma unroll
    for (int fr = 0; fr < 2; ++fr)
#pragma unroll
        for (int r = 0; r < 4; ++r) {
            int gm = m0 + wv * 32 + fr * 16 + 4 * lg + r;
            float v[4];
#pragma unroll
            for (int fc = 0; fc < 4; ++fc) v[fc] = acc[fr][fc][r] + pb4[fc];
            float s = v[0] + v[1] + v[2] + v[3];
            s += __shfl_xor(s, 1); s += __shfl_xor(s, 2);
            s += __shfl_xor(s, 4); s += __shfl_xor(s, 8);
            float mu = s * (1.f / 64.f);
            float q = 0.f;
#pragma unroll
            for (int fc = 0; fc < 4; ++fc) { v[fc] -= mu; q = fmaf(v[fc], v[fc], q); }
            q += __shfl_xor(q, 1); q += __shfl_xor(q, 2);
            q += __shfl_xor(q, 4); q += __shfl_xor(q, 8);
            float inv = rsqrtf(q * (1.f / 64.f) + 1e-5f);
            if (gm < N_NODES) {
#pragma unroll
                for (int fc = 0; fc < 4; ++fc)
                    out[(size_t)gm * NCLASS + fc * 16 + lr] = v[fc] * inv * g4[fc] + b4[fc];
            }
        }
}

extern "C" void kernel_launch(void* const* d_in, const int* in_sizes, int n_in,
                              void* d_out, int out_size, void* d_ws, size_t ws_size,
                              hipStream_t stream) {
    const float* x      = (const float*)d_in[0];
    const int*   ei     = (const int*)  d_in[1];
    const float* eww    = (const float*)d_in[2];
    const float* w1     = (const float*)d_in[3];
    const float* b1v    = (const float*)d_in[4];
    const float* w2     = (const float*)d_in[5];
    const float* b2v    = (const float*)d_in[6];
    const float* proj_w = (const float*)d_in[7];
    const float* proj_b = (const float*)d_in[8];
    const float* ln_g   = (const float*)d_in[9];
    const float* ln_b   = (const float*)d_in[10];
    float* out = (float*)d_out;

    char* ws = (char*)d_ws;
    size_t off = 0;
    auto alloc = [&](size_t bytes) -> void* {
        void* p = ws + off;
        off = (off + bytes + 255) & ~(size_t)255;
        return p;
    };
    u16*   aggx   = (u16*)  alloc((size_t)N_NODES * KAGG * 2);    // 102.4 MB
    u8*    nb     = (u8*)   alloc((size_t)N_NODES * NAB);         // 3.2 MB (fp8)
    u16*   xb     = (u16*)  alloc((size_t)N_NODES * NFEAT * 2);   // 12.8 MB
    u16*   WpT    = (u16*)  alloc((size_t)NAB * NFEAT * 2);       // 16 KB
    u16*   pwT    = (u16*)  alloc((size_t)NCLASS * KAGG * 2);     // 128 KB
    u32*   esb    = (u32*)  alloc((size_t)ET_EDGES * 32);         // 27.2 MB
    int*   rank   = (int*)  alloc((size_t)N_EDGES * 4);           // 3.2 MB
    float* dslot  = (float*)alloc(NSLOT * NHEADS * 4);            // 2 KB
    int*   deg    = (int*)  alloc((size_t)N_NODES * 4);
    int*   rowptr = (int*)  alloc((size_t)(N_NODES + 1) * 4);
    int*   bsum   = (int*)  alloc(64 * 4);
    int*   boff   = (int*)  alloc(64 * 4);
    if (off > ws_size) return;

    hipMemsetAsync(deg, 0, (size_t)N_NODES * 4, stream);
    hipMemsetAsync(dslot, 0, NSLOT * NHEADS * 4, stream);

    k_prep<<<288 + (N_EDGES + 255) / 256, 256, 0, stream>>>(w1, proj_w, ei, WpT, pwT, deg, rank);
    k_scan1<<<NBLK_SCAN, 1024, 0, stream>>>(deg, rowptr, bsum);
    k_scan2<<<1, 64, 0, stream>>>(bsum, boff, rowptr);
    k_scan3<<<(N_NODES + 255) / 256, 256, 0, stream>>>(rowptr, boff);

    k_gemm<<<(N_NODES + 127) / 128, 256, 0, stream>>>(x, WpT, b1v, nb, xb);

    k_edges<<<(ET_EDGES + 255) / 256, 256, 0, stream>>>(nb, ei, rank, rowptr, eww, w2, b2v,
                                                        esb, dslot);
    k_agg<<<(N_NODES + 3) / 4, 256, 0, stream>>>(xb, esb, rowptr, dslot, aggx);
    k_out<<<(N_NODES + 127) / 128, 256, 0, stream>>>(aggx, pwT, proj_b, ln_g, ln_b, out);
}

// Round 14
// 193.739 us; speedup vs baseline: 1.2609x; 1.2609x over previous
//
#include <hip/hip_runtime.h>
#include <hip/hip_bf16.h>

#define N_NODES 50000
#define N_EDGES 800000
#define ET_EDGES (N_EDGES + N_NODES)   // 850000
#define NFEAT 128
#define NCLASS 64
#define NHEADS 8
#define HIDDEN 32
#define NAB 64            // nb row: a(32) | b(32) fp8, b has b1 folded in
#define KAGG 1024         // 8 heads * 128 feat
#define NSLOT 64          // denom slot hashing
typedef unsigned short u16;
typedef unsigned int u32;
typedef unsigned char u8;

typedef __attribute__((ext_vector_type(8))) short bf16x8;
typedef __attribute__((ext_vector_type(4))) float f32x4;
typedef __attribute__((ext_vector_type(2))) float f32x2;

static __device__ __forceinline__ u16 f2bf(float f) {
    u32 u = __float_as_uint(f);
    return (u16)((u + 0x7fffu + ((u >> 16) & 1u)) >> 16);  // RNE
}
static __device__ __forceinline__ u32 pack2bf(float lo, float hi) {
    return (u32)f2bf(lo) | ((u32)f2bf(hi) << 16);
}
static __device__ __forceinline__ float bfl(u32 u) { return __uint_as_float(u << 16); }
static __device__ __forceinline__ float bfh(u32 u) { return __uint_as_float(u & 0xffff0000u); }
static __device__ __forceinline__ u8 f2fp8(float f) {
    return (u8)(__builtin_amdgcn_cvt_pk_fp8_f32(f, 0.f, 0, false) & 0xff);
}

// ---- merged prep: WpT pack | pwT pack | deg histogram + per-edge rank capture ----
__global__ __launch_bounds__(256) void k_prep(const float* __restrict__ w1,
                                              const float* __restrict__ proj_w,
                                              const int* __restrict__ ei,
                                              u16* __restrict__ WpT,
                                              u16* __restrict__ pwT,
                                              int* __restrict__ deg,
                                              int* __restrict__ rank) {
    int b = blockIdx.x;
    if (b < 32) {                                   // WpT [64][128] bf16
        int idx = b * 256 + threadIdx.x;
        int o = idx / NFEAT, k = idx % NFEAT;
        float v = (o < HIDDEN) ? w1[k * HIDDEN + o]
                               : w1[(NFEAT + k) * HIDDEN + (o - HIDDEN)];
        WpT[idx] = f2bf(v);
    } else if (b < 32 + 256) {                      // pwT [64][1024] bf16
        int idx = (b - 32) * 256 + threadIdx.x;
        int c = idx >> 10, k = idx & (KAGG - 1);
        pwT[idx] = f2bf(proj_w[(size_t)k * NCLASS + c]);
    } else {                                        // deg histogram; rank = slot within node
        int e = (b - 288) * 256 + threadIdx.x;
        if (e < N_EDGES) rank[e] = atomicAdd(&deg[ei[N_EDGES + e]], 1);
    }
}

// ---- GEMM1: nb[N][64] fp8 = x[N][128] @ WpT^T (+b1 on b-cols); write-through xb bf16 ----
#define ROWP 136
__global__ __launch_bounds__(256) void k_gemm(const float* __restrict__ x,
                                              const u16* __restrict__ WpT,
                                              const float* __restrict__ b1v,
                                              u8* __restrict__ nb,
                                              u16* __restrict__ xb) {
    __shared__ __align__(16) u16 As[128 * ROWP];
    __shared__ __align__(16) u16 Bs[64 * ROWP];
    int tid = threadIdx.x;
    int m0 = blockIdx.x * 128;
    int wv = tid >> 6, l = tid & 63, lr = l & 15, lg = l >> 4;

#pragma unroll
    for (int p = 0; p < 8; ++p) {
        int idx = tid + p * 256;
        int row = idx >> 4, fo = idx & 15;
        int gm = m0 + row;
        float4 f0 = make_float4(0.f,0.f,0.f,0.f), f1 = f0;
        if (gm < N_NODES) {
            const float* xp = x + (size_t)gm * NFEAT + fo * 8;
            f0 = *(const float4*)xp;
            f1 = *(const float4*)(xp + 4);
        }
        uint4 v;
        v.x = pack2bf(f0.x, f0.y); v.y = pack2bf(f0.z, f0.w);
        v.z = pack2bf(f1.x, f1.y); v.w = pack2bf(f1.z, f1.w);
        *(uint4*)&As[row * ROWP + fo * 8] = v;
        if (gm < N_NODES) *(uint4*)(xb + (size_t)gm * NFEAT + fo * 8) = v;
    }
#pragma unroll
    for (int p = 0; p < 4; ++p) {
        int idx = tid + p * 256;
        int col = idx >> 4, fo = idx & 15;
        *(uint4*)&Bs[col * ROWP + fo * 8] = *(const uint4*)(WpT + (size_t)col * NFEAT + fo * 8);
    }
    __syncthreads();
    union FR { uint4 q; bf16x8 v; };
    f32x4 acc[2][4];
#pragma unroll
    for (int fr = 0; fr < 2; ++fr)
#pragma unroll
        for (int fc = 0; fc < 4; ++fc) acc[fr][fc] = (f32x4){0.f, 0.f, 0.f, 0.f};
#pragma unroll
    for (int ks = 0; ks < 4; ++ks) {
        int k0 = ks * 32;
        FR a0, a1, b0, b1, b2, b3;
        a0.q = *(const uint4*)&As[(wv * 32 + 0  + lr) * ROWP + k0 + 8 * lg];
        a1.q = *(const uint4*)&As[(wv * 32 + 16 + lr) * ROWP + k0 + 8 * lg];
        b0.q = *(const uint4*)&Bs[(0  + lr) * ROWP + k0 + 8 * lg];
        b1.q = *(const uint4*)&Bs[(16 + lr) * ROWP + k0 + 8 * lg];
        b2.q = *(const uint4*)&Bs[(32 + lr) * ROWP + k0 + 8 * lg];
        b3.q = *(const uint4*)&Bs[(48 + lr) * ROWP + k0 + 8 * lg];
        acc[0][0] = __builtin_amdgcn_mfma_f32_16x16x32_bf16(a0.v, b0.v, acc[0][0], 0, 0, 0);
        acc[0][1] = __builtin_amdgcn_mfma_f32_16x16x32_bf16(a0.v, b1.v, acc[0][1], 0, 0, 0);
        acc[0][2] = __builtin_amdgcn_mfma_f32_16x16x32_bf16(a0.v, b2.v, acc[0][2], 0, 0, 0);
        acc[0][3] = __builtin_amdgcn_mfma_f32_16x16x32_bf16(a0.v, b3.v, acc[0][3], 0, 0, 0);
        acc[1][0] = __builtin_amdgcn_mfma_f32_16x16x32_bf16(a1.v, b0.v, acc[1][0], 0, 0, 0);
        acc[1][1] = __builtin_amdgcn_mfma_f32_16x16x32_bf16(a1.v, b1.v, acc[1][1], 0, 0, 0);
        acc[1][2] = __builtin_amdgcn_mfma_f32_16x16x32_bf16(a1.v, b2.v, acc[1][2], 0, 0, 0);
        acc[1][3] = __builtin_amdgcn_mfma_f32_16x16x32_bf16(a1.v, b3.v, acc[1][3], 0, 0, 0);
    }
    // D[row = wv*32+fr*16+4*lg+r][col = fc*16+lr] ; b1 folded into cols 32..63; fp8 store
    float badd[4];
    badd[0] = 0.f; badd[1] = 0.f; badd[2] = b1v[lr]; badd[3] = b1v[16 + lr];
#pragma unroll
    for (int fr = 0; fr < 2; ++fr)
#pragma unroll
        for (int fc = 0; fc < 4; ++fc)
#pragma unroll
            for (int r = 0; r < 4; ++r) {
                int gm = m0 + wv * 32 + fr * 16 + 4 * lg + r;
                if (gm < N_NODES)
                    nb[(size_t)gm * NAB + fc * 16 + lr] = f2fp8(acc[fr][fc][r] + badd[fc]);
            }
}

// ---- scan (3 kernels); scan1 adds +1 per node for the self-loop ----
__global__ __launch_bounds__(1024) void k_scan1(const int* __restrict__ deg,
                                                int* __restrict__ rowptr,
                                                int* __restrict__ bsum) {
    __shared__ int sd[1024];
    int tid = threadIdx.x;
    int i = blockIdx.x * 1024 + tid;
    int v = (i < N_NODES) ? deg[i] + 1 : 0;
    sd[tid] = v;
    __syncthreads();
    for (int off = 1; off < 1024; off <<= 1) {
        int t = (tid >= off) ? sd[tid - off] : 0;
        __syncthreads();
        sd[tid] += t;
        __syncthreads();
    }
    if (i < N_NODES) rowptr[i] = sd[tid] - v;
    if (tid == 1023) bsum[blockIdx.x] = sd[1023];
}
#define NBLK_SCAN 49
__global__ __launch_bounds__(64) void k_scan2(const int* __restrict__ bsum,
                                              int* __restrict__ boff,
                                              int* __restrict__ rowptr) {
    int l = threadIdx.x;
    int orig = (l < NBLK_SCAN) ? bsum[l] : 0;
    int v = orig;
    for (int off = 1; off < 64; off <<= 1) {
        int t = __shfl_up(v, off);
        if (l >= off) v += t;
    }
    if (l < NBLK_SCAN) boff[l] = v - orig;
    if (l == 63) rowptr[N_NODES] = v;
}
__global__ __launch_bounds__(256) void k_scan3(int* __restrict__ rowptr,
                                               const int* __restrict__ boff) {
    int i = blockIdx.x * 256 + threadIdx.x;
    if (i >= N_NODES) return;
    rowptr[i] += boff[i >> 10];
}

// ---- fused per-edge MLP + gate + exp + CSR scatter; NO atomics (rank-based slot) ----
__global__ __launch_bounds__(256) void k_edges(const u8* __restrict__ nb,
                                               const int* __restrict__ ei,
                                               const int* __restrict__ rank,
                                               const int* __restrict__ rowptr,
                                               const float* __restrict__ eww,
                                               const float* __restrict__ w2,
                                               const float* __restrict__ b2v,
                                               uint4* __restrict__ esb,
                                               float* __restrict__ dslot) {
    int e = blockIdx.x * 256 + threadIdx.x;
    bool valid = e < ET_EDGES;
    int s = 0, d = 0, pos = 0;
    if (valid) {
        if (e < N_EDGES) {
            s = ei[e]; d = ei[N_EDGES + e];
            pos = rowptr[d] + rank[e];          // unique slot, no RMW
        } else {
            s = d = e - N_EDGES;
            pos = rowptr[d + 1] - 1;            // self-loop takes the reserved last slot
        }
    }
    // eww loads depend only on e: issue before anything needs them
    int ee = valid ? e : 0;
    float ew[NHEADS];
#pragma unroll
    for (int t = 0; t < NHEADS; ++t) ew[t] = eww[(size_t)t * ET_EDGES + ee];

    const uint4* rp = (const uint4*)(nb + (size_t)s * NAB);   // a = bytes 0..31
    const uint4* rq = (const uint4*)(nb + (size_t)d * NAB);   // b = bytes 32..63
    uint4 Au = rp[0], Av = rp[1];
    uint4 Bu = rq[2], Bv = rq[3];

    float h[HIDDEN];
#define DEC8(au, bu, base) { \
        f32x2 al = __builtin_amdgcn_cvt_pk_f32_fp8((int)(au), false); \
        f32x2 ah = __builtin_amdgcn_cvt_pk_f32_fp8((int)(au), true);  \
        f32x2 bl = __builtin_amdgcn_cvt_pk_f32_fp8((int)(bu), false); \
        f32x2 bh = __builtin_amdgcn_cvt_pk_f32_fp8((int)(bu), true);  \
        h[base+0] = fmaxf(al.x + bl.x, 0.f); h[base+1] = fmaxf(al.y + bl.y, 0.f); \
        h[base+2] = fmaxf(ah.x + bh.x, 0.f); h[base+3] = fmaxf(ah.y + bh.y, 0.f); }
    DEC8(Au.x, Bu.x, 0)  DEC8(Au.y, Bu.y, 4)  DEC8(Au.z, Bu.z, 8)  DEC8(Au.w, Bu.w, 12)
    DEC8(Av.x, Bv.x, 16) DEC8(Av.y, Bv.y, 20) DEC8(Av.z, Bv.z, 24) DEC8(Av.w, Bv.w, 28)
#undef DEC8

    float z[NHEADS];
#pragma unroll
    for (int t = 0; t < NHEADS; ++t) z[t] = 0.f;
#pragma unroll
    for (int j = 0; j < HIDDEN; ++j)
#pragma unroll
        for (int t = 0; t < NHEADS; ++t) z[t] = fmaf(h[j], w2[j * NHEADS + t], z[t]);

    float pe[NHEADS];
#pragma unroll
    for (int t = 0; t < NHEADS; ++t) {
        float dyn = 1.f / (1.f + __expf(-(z[t] + b2v[t])));
        float tw  = ew[t] * dyn;
        tw = fmaxf(tw, 0.01f * tw);                 // leaky_relu
        pe[t] = valid ? __expf(tw) : 0.f;
    }
    if (valid) {
        uint4 q0, q1;
        q0.x = pack2bf(pe[0], pe[1]); q0.y = pack2bf(pe[2], pe[3]);
        q0.z = pack2bf(pe[4], pe[5]); q0.w = pack2bf(pe[6], pe[7]);
        q1 = make_uint4((u32)s, 0u, 0u, 0u);
        uint4* dst = esb + 2 * (size_t)pos;         // one 32B record: single line touch
        dst[0] = q0;
        dst[1] = q1;
    }
    __shared__ float blk[NHEADS];
    if (threadIdx.x < NHEADS) blk[threadIdx.x] = 0.f;
    __syncthreads();
    int lane = threadIdx.x & 63;
#pragma unroll
    for (int t = 0; t < NHEADS; ++t) {
        float v = pe[t];
        for (int off = 32; off > 0; off >>= 1) v += __shfl_xor(v, off);
        if (lane == 0) atomicAdd(&blk[t], v);
    }
    __syncthreads();
    if (threadIdx.x < NHEADS)
        atomicAdd(&dslot[(blockIdx.x & (NSLOT - 1)) * NHEADS + threadIdx.x], blk[threadIdx.x]);
}

// ---- aggregate: SGPR record loads (4-edge unroll) + v_pk_fma_f32; bf16 aggx out ----
__global__ __launch_bounds__(256) void k_agg(const u16* __restrict__ xb,
                                             const uint4* __restrict__ esb,
                                             const int* __restrict__ rowptr,
                                             const float* __restrict__ dslot,
                                             u16* __restrict__ aggx) {
    int lane = threadIdx.x & 63;
    int n = __builtin_amdgcn_readfirstlane(blockIdx.x * 4 + (threadIdx.x >> 6));
    if (n >= N_NODES) return;
    f32x2 acc[8];
#pragma unroll
    for (int h = 0; h < 8; ++h) acc[h] = (f32x2){0.f, 0.f};
    int beg = __builtin_amdgcn_readfirstlane(rowptr[n]);
    int end = __builtin_amdgcn_readfirstlane(rowptr[n + 1]);
    const u32* rec = (const u32*)esb;          // uniform base; idx uniform -> s_load
    const u16* xrow = xb + 2 * lane;

#define WACC(w0u, w1u, w2u, w3u, xv) { \
        acc[0] = __builtin_elementwise_fma((f32x2){bfl(w0u), bfl(w0u)}, xv, acc[0]); \
        acc[1] = __builtin_elementwise_fma((f32x2){bfh(w0u), bfh(w0u)}, xv, acc[1]); \
        acc[2] = __builtin_elementwise_fma((f32x2){bfl(w1u), bfl(w1u)}, xv, acc[2]); \
        acc[3] = __builtin_elementwise_fma((f32x2){bfh(w1u), bfh(w1u)}, xv, acc[3]); \
        acc[4] = __builtin_elementwise_fma((f32x2){bfl(w2u), bfl(w2u)}, xv, acc[4]); \
        acc[5] = __builtin_elementwise_fma((f32x2){bfh(w2u), bfh(w2u)}, xv, acc[5]); \
        acc[6] = __builtin_elementwise_fma((f32x2){bfl(w3u), bfl(w3u)}, xv, acc[6]); \
        acc[7] = __builtin_elementwise_fma((f32x2){bfh(w3u), bfh(w3u)}, xv, acc[7]); }

    int idx = beg;
    for (; idx + 4 <= end; idx += 4) {
        size_t r = (size_t)idx * 8;            // u32 index of record; 4 records = 128 B scalar
        u32 a0 = rec[r + 0],  a1 = rec[r + 1],  a2 = rec[r + 2],  a3 = rec[r + 3];
        int  s0 = (int)rec[r + 4];
        u32 b0 = rec[r + 8],  b1 = rec[r + 9],  b2 = rec[r + 10], b3 = rec[r + 11];
        int  s1 = (int)rec[r + 12];
        u32 c0 = rec[r + 16], c1 = rec[r + 17], c2 = rec[r + 18], c3 = rec[r + 19];
        int  s2 = (int)rec[r + 20];
        u32 d0 = rec[r + 24], d1 = rec[r + 25], d2 = rec[r + 26], d3 = rec[r + 27];
        int  s3 = (int)rec[r + 28];
        u32 xu0 = *(const u32*)(xrow + (size_t)s0 * NFEAT);
        u32 xu1 = *(const u32*)(xrow + (size_t)s1 * NFEAT);
        u32 xu2 = *(const u32*)(xrow + (size_t)s2 * NFEAT);
        u32 xu3 = *(const u32*)(xrow + (size_t)s3 * NFEAT);
        f32x2 xv0 = {bfl(xu0), bfh(xu0)};
        f32x2 xv1 = {bfl(xu1), bfh(xu1)};
        f32x2 xv2 = {bfl(xu2), bfh(xu2)};
        f32x2 xv3 = {bfl(xu3), bfh(xu3)};
        WACC(a0, a1, a2, a3, xv0)
        WACC(b0, b1, b2, b3, xv1)
        WACC(c0, c1, c2, c3, xv2)
        WACC(d0, d1, d2, d3, xv3)
    }
    for (; idx < end; ++idx) {
        size_t r = (size_t)idx * 8;
        u32 a0 = rec[r + 0], a1 = rec[r + 1], a2 = rec[r + 2], a3 = rec[r + 3];
        int  s0 = (int)rec[r + 4];
        u32 xu0 = *(const u32*)(xrow + (size_t)s0 * NFEAT);
        f32x2 xv0 = {bfl(xu0), bfh(xu0)};
        WACC(a0, a1, a2, a3, xv0)
    }
#undef WACC
    // epilogue: wave-parallel denom reduce over 64 slots (lane = slot); regs free here
    float4 da = *(const float4*)(dslot + lane * NHEADS);
    float4 db = *(const float4*)(dslot + lane * NHEADS + 4);
#pragma unroll
    for (int off = 32; off > 0; off >>= 1) {
        da.x += __shfl_xor(da.x, off); da.y += __shfl_xor(da.y, off);
        da.z += __shfl_xor(da.z, off); da.w += __shfl_xor(da.w, off);
        db.x += __shfl_xor(db.x, off); db.y += __shfl_xor(db.y, off);
        db.z += __shfl_xor(db.z, off); db.w += __shfl_xor(db.w, off);
    }
    u16* dst = aggx + (size_t)n * KAGG + 2 * lane;
    *(u32*)(dst + 0 * NFEAT) = pack2bf(acc[0][0] / da.x, acc[0][1] / da.x);
    *(u32*)(dst + 1 * NFEAT) = pack2bf(acc[1][0] / da.y, acc[1][1] / da.y);
    *(u32*)(dst + 2 * NFEAT) = pack2bf(acc[2][0] / da.z, acc[2][1] / da.z);
    *(u32*)(dst + 3 * NFEAT) = pack2bf(acc[3][0] / da.w, acc[3][1] / da.w);
    *(u32*)(dst + 4 * NFEAT) = pack2bf(acc[4][0] / db.x, acc[4][1] / db.x);
    *(u32*)(dst + 5 * NFEAT) = pack2bf(acc[5][0] / db.y, acc[5][1] / db.y);
    *(u32*)(dst + 6 * NFEAT) = pack2bf(acc[6][0] / db.z, acc[6][1] / db.z);
    *(u32*)(dst + 7 * NFEAT) = pack2bf(acc[7][0] / db.w, acc[7][1] / db.w);
}

// ---- GEMM2 + bias + LayerNorm: out[N][64] = LN(aggx[N][1024] @ pwT^T + proj_b) ----
__global__ __launch_bounds__(256) void k_out(const u16* __restrict__ aggx,
                                             const u16* __restrict__ pwT,
                                             const float* __restrict__ proj_b,
                                             const float* __restrict__ ln_g,
                                             const float* __restrict__ ln_b,
                                             float* __restrict__ out) {
    __shared__ __align__(16) u16 As[128 * ROWP];
    __shared__ __align__(16) u16 Bs[64 * ROWP];
    int tid = threadIdx.x;
    int m0 = blockIdx.x * 128;
    int wv = tid >> 6, l = tid & 63, lr = l & 15, lg = l >> 4;
    union FR { uint4 q; bf16x8 v; };
    f32x4 acc[2][4];
#pragma unroll
    for (int fr = 0; fr < 2; ++fr)
#pragma unroll
        for (int fc = 0; fc < 4; ++fc) acc[fr][fc] = (f32x4){0.f, 0.f, 0.f, 0.f};

    for (int kt = 0; kt < 8; ++kt) {
        int kb = kt * 128;
        __syncthreads();
#pragma unroll
        for (int p = 0; p < 8; ++p) {
            int idx = tid + p * 256;
            int row = idx >> 4, fo = idx & 15;
            int gm = m0 + row;
            uint4 v = make_uint4(0u, 0u, 0u, 0u);
            if (gm < N_NODES) v = *(const uint4*)(aggx + (size_t)gm * KAGG + kb + fo * 8);
            *(uint4*)&As[row * ROWP + fo * 8] = v;
        }
#pragma unroll
        for (int p = 0; p < 4; ++p) {
            int idx = tid + p * 256;
            int col = idx >> 4, fo = idx & 15;
            *(uint4*)&Bs[col * ROWP + fo * 8] =
                *(const uint4*)(pwT + (size_t)col * KAGG + kb + fo * 8);
        }
        __syncthreads();
#pragma unroll
        for (int ks = 0; ks < 4; ++ks) {
            int k0 = ks * 32;
            FR a0, a1, b0, b1, b2, b3;
            a0.q = *(const uint4*)&As[(wv * 32 + 0  + lr) * ROWP + k0 + 8 * lg];
            a1.q = *(const uint4*)&As[(wv * 32 + 16 + lr) * ROWP + k0 + 8 * lg];
            b0.q = *(const uint4*)&Bs[(0  + lr) * ROWP + k0 + 8 * lg];
            b1.q = *(const uint4*)&Bs[(16 + lr) * ROWP + k0 + 8 * lg];
            b2.q = *(const uint4*)&Bs[(32 + lr) * ROWP + k0 + 8 * lg];
            b3.q = *(const uint4*)&Bs[(48 + lr) * ROWP + k0 + 8 * lg];
            acc[0][0] = __builtin_amdgcn_mfma_f32_16x16x32_bf16(a0.v, b0.v, acc[0][0], 0, 0, 0);
            acc[0][1] = __builtin_amdgcn_mfma_f32_16x16x32_bf16(a0.v, b1.v, acc[0][1], 0, 0, 0);
            acc[0][2] = __builtin_amdgcn_mfma_f32_16x16x32_bf16(a0.v, b2.v, acc[0][2], 0, 0, 0);
            acc[0][3] = __builtin_amdgcn_mfma_f32_16x16x32_bf16(a0.v, b3.v, acc[0][3], 0, 0, 0);
            acc[1][0] = __builtin_amdgcn_mfma_f32_16x16x32_bf16(a1.v, b0.v, acc[1][0], 0, 0, 0);
            acc[1][1] = __builtin_amdgcn_mfma_f32_16x16x32_bf16(a1.v, b1.v, acc[1][1], 0, 0, 0);
            acc[1][2] = __builtin_amdgcn_mfma_f32_16x16x32_bf16(a1.v, b2.v, acc[1][2], 0, 0, 0);
            acc[1][3] = __builtin_amdgcn_mfma_f32_16x16x32_bf16(a1.v, b3.v, acc[1][3], 0, 0, 0);
        }
    }
    float pb4[4], g4[4], b4[4];
#pragma unroll
    for (int fc = 0; fc < 4; ++fc) {
        pb4[fc] = proj_b[fc * 16 + lr];
        g4[fc]  = ln_g[fc * 16 + lr];
        b4[fc]  = ln_b[fc * 16 + lr];
    }
#pragma unroll
    for (int fr = 0; fr < 2; ++fr)
#pragma unroll
        for (int r = 0; r < 4; ++r) {
            int gm = m0 + wv * 32 + fr * 16 + 4 * lg + r;
            float v[4];
#pragma unroll
            for (int fc = 0; fc < 4; ++fc) v[fc] = acc[fr][fc][r] + pb4[fc];
            float s = v[0] + v[1] + v[2] + v[3];
            s += __shfl_xor(s, 1); s += __shfl_xor(s, 2);
            s += __shfl_xor(s, 4); s += __shfl_xor(s, 8);
            float mu = s * (1.f / 64.f);
            float q = 0.f;
#pragma unroll
            for (int fc = 0; fc < 4; ++fc) { v[fc] -= mu; q = fmaf(v[fc], v[fc], q); }
            q += __shfl_xor(q, 1); q += __shfl_xor(q, 2);
            q += __shfl_xor(q, 4); q += __shfl_xor(q, 8);
            float inv = rsqrtf(q * (1.f / 64.f) + 1e-5f);
            if (gm < N_NODES) {
#pragma unroll
                for (int fc = 0; fc < 4; ++fc)
                    out[(size_t)gm * NCLASS + fc * 16 + lr] = v[fc] * inv * g4[fc] + b4[fc];
            }
        }
}

extern "C" void kernel_launch(void* const* d_in, const int* in_sizes, int n_in,
                              void* d_out, int out_size, void* d_ws, size_t ws_size,
                              hipStream_t stream) {
    const float* x      = (const float*)d_in[0];
    const int*   ei     = (const int*)  d_in[1];
    const float* eww    = (const float*)d_in[2];
    const float* w1     = (const float*)d_in[3];
    const float* b1v    = (const float*)d_in[4];
    const float* w2     = (const float*)d_in[5];
    const float* b2v    = (const float*)d_in[6];
    const float* proj_w = (const float*)d_in[7];
    const float* proj_b = (const float*)d_in[8];
    const float* ln_g   = (const float*)d_in[9];
    const float* ln_b   = (const float*)d_in[10];
    float* out = (float*)d_out;

    char* ws = (char*)d_ws;
    size_t off = 0;
    auto alloc = [&](size_t bytes) -> void* {
        void* p = ws + off;
        off = (off + bytes + 255) & ~(size_t)255;
        return p;
    };
    u16*   aggx   = (u16*)  alloc((size_t)N_NODES * KAGG * 2);    // 102.4 MB
    u8*    nb     = (u8*)   alloc((size_t)N_NODES * NAB);         // 3.2 MB (fp8)
    u16*   xb     = (u16*)  alloc((size_t)N_NODES * NFEAT * 2);   // 12.8 MB
    u16*   WpT    = (u16*)  alloc((size_t)NAB * NFEAT * 2);       // 16 KB
    u16*   pwT    = (u16*)  alloc((size_t)NCLASS * KAGG * 2);     // 128 KB
    uint4* esb    = (uint4*)alloc((size_t)ET_EDGES * 32);         // 27.2 MB
    int*   rank   = (int*)  alloc((size_t)N_EDGES * 4);           // 3.2 MB
    float* dslot  = (float*)alloc(NSLOT * NHEADS * 4);            // 2 KB
    int*   deg    = (int*)  alloc((size_t)N_NODES * 4);
    int*   rowptr = (int*)  alloc((size_t)(N_NODES + 1) * 4);
    int*   bsum   = (int*)  alloc(64 * 4);
    int*   boff   = (int*)  alloc(64 * 4);
    if (off > ws_size) return;

    hipMemsetAsync(deg, 0, (size_t)N_NODES * 4, stream);
    hipMemsetAsync(dslot, 0, NSLOT * NHEADS * 4, stream);

    k_prep<<<288 + (N_EDGES + 255) / 256, 256, 0, stream>>>(w1, proj_w, ei, WpT, pwT, deg, rank);
    k_scan1<<<NBLK_SCAN, 1024, 0, stream>>>(deg, rowptr, bsum);
    k_scan2<<<1, 64, 0, stream>>>(bsum, boff, rowptr);
    k_scan3<<<(N_NODES + 255) / 256, 256, 0, stream>>>(rowptr, boff);

    k_gemm<<<(N_NODES + 127) / 128, 256, 0, stream>>>(x, WpT, b1v, nb, xb);

    k_edges<<<(ET_EDGES + 255) / 256, 256, 0, stream>>>(nb, ei, rank, rowptr, eww, w2, b2v,
                                                        esb, dslot);
    k_agg<<<(N_NODES + 3) / 4, 256, 0, stream>>>(xb, esb, rowptr, dslot, aggx);
    k_out<<<(N_NODES + 127) / 128, 256, 0, stream>>>(aggx, pwT, proj_b, ln_g, ln_b, out);
}

// Round 15
// 193.433 us; speedup vs baseline: 1.2629x; 1.0016x over previous
//
#include <hip/hip_runtime.h>
#include <hip/hip_bf16.h>

#define N_NODES 50000
#define N_EDGES 800000
#define ET_EDGES (N_EDGES + N_NODES)   // 850000
#define NFEAT 128
#define NCLASS 64
#define NHEADS 8
#define HIDDEN 32
#define NAB 64            // nb row: a(32) | b(32) fp8, b has b1 folded in
#define KAGG 1024         // 8 heads * 128 feat
#define NSLOT 64          // denom slot hashing
typedef unsigned short u16;
typedef unsigned int u32;
typedef unsigned char u8;

typedef __attribute__((ext_vector_type(8))) short bf16x8;
typedef __attribute__((ext_vector_type(4))) float f32x4;
typedef __attribute__((ext_vector_type(2))) float f32x2;

static __device__ __forceinline__ u16 f2bf(float f) {
    u32 u = __float_as_uint(f);
    return (u16)((u + 0x7fffu + ((u >> 16) & 1u)) >> 16);  // RNE
}
static __device__ __forceinline__ u32 pack2bf(float lo, float hi) {
    return (u32)f2bf(lo) | ((u32)f2bf(hi) << 16);
}
static __device__ __forceinline__ float bfl(u32 u) { return __uint_as_float(u << 16); }
static __device__ __forceinline__ float bfh(u32 u) { return __uint_as_float(u & 0xffff0000u); }
static __device__ __forceinline__ u8 f2fp8(float f) {
    return (u8)(__builtin_amdgcn_cvt_pk_fp8_f32(f, 0.f, 0, false) & 0xff);
}

// ---- merged prep: WpT pack | pwT pack | deg histogram + per-edge rank capture ----
__global__ __launch_bounds__(256) void k_prep(const float* __restrict__ w1,
                                              const float* __restrict__ proj_w,
                                              const int* __restrict__ ei,
                                              u16* __restrict__ WpT,
                                              u16* __restrict__ pwT,
                                              int* __restrict__ deg,
                                              int* __restrict__ rank) {
    int b = blockIdx.x;
    if (b < 32) {                                   // WpT [64][128] bf16
        int idx = b * 256 + threadIdx.x;
        int o = idx / NFEAT, k = idx % NFEAT;
        float v = (o < HIDDEN) ? w1[k * HIDDEN + o]
                               : w1[(NFEAT + k) * HIDDEN + (o - HIDDEN)];
        WpT[idx] = f2bf(v);
    } else if (b < 32 + 256) {                      // pwT [64][1024] bf16
        int idx = (b - 32) * 256 + threadIdx.x;
        int c = idx >> 10, k = idx & (KAGG - 1);
        pwT[idx] = f2bf(proj_w[(size_t)k * NCLASS + c]);
    } else {                                        // deg histogram; rank = slot within node
        int e = (b - 288) * 256 + threadIdx.x;
        if (e < N_EDGES) rank[e] = atomicAdd(&deg[ei[N_EDGES + e]], 1);
    }
}

// ---- GEMM1: nb[N][64] fp8 = x[N][128] @ WpT^T (+b1 on b-cols); write-through xb bf16 ----
#define ROWP 136
__global__ __launch_bounds__(256) void k_gemm(const float* __restrict__ x,
                                              const u16* __restrict__ WpT,
                                              const float* __restrict__ b1v,
                                              u8* __restrict__ nb,
                                              u16* __restrict__ xb) {
    __shared__ __align__(16) u16 As[128 * ROWP];
    __shared__ __align__(16) u16 Bs[64 * ROWP];
    int tid = threadIdx.x;
    int m0 = blockIdx.x * 128;
    int wv = tid >> 6, l = tid & 63, lr = l & 15, lg = l >> 4;

#pragma unroll
    for (int p = 0; p < 8; ++p) {
        int idx = tid + p * 256;
        int row = idx >> 4, fo = idx & 15;
        int gm = m0 + row;
        float4 f0 = make_float4(0.f,0.f,0.f,0.f), f1 = f0;
        if (gm < N_NODES) {
            const float* xp = x + (size_t)gm * NFEAT + fo * 8;
            f0 = *(const float4*)xp;
            f1 = *(const float4*)(xp + 4);
        }
        uint4 v;
        v.x = pack2bf(f0.x, f0.y); v.y = pack2bf(f0.z, f0.w);
        v.z = pack2bf(f1.x, f1.y); v.w = pack2bf(f1.z, f1.w);
        *(uint4*)&As[row * ROWP + fo * 8] = v;
        if (gm < N_NODES) *(uint4*)(xb + (size_t)gm * NFEAT + fo * 8) = v;
    }
#pragma unroll
    for (int p = 0; p < 4; ++p) {
        int idx = tid + p * 256;
        int col = idx >> 4, fo = idx & 15;
        *(uint4*)&Bs[col * ROWP + fo * 8] = *(const uint4*)(WpT + (size_t)col * NFEAT + fo * 8);
    }
    __syncthreads();
    union FR { uint4 q; bf16x8 v; };
    f32x4 acc[2][4];
#pragma unroll
    for (int fr = 0; fr < 2; ++fr)
#pragma unroll
        for (int fc = 0; fc < 4; ++fc) acc[fr][fc] = (f32x4){0.f, 0.f, 0.f, 0.f};
#pragma unroll
    for (int ks = 0; ks < 4; ++ks) {
        int k0 = ks * 32;
        FR a0, a1, b0, b1, b2, b3;
        a0.q = *(const uint4*)&As[(wv * 32 + 0  + lr) * ROWP + k0 + 8 * lg];
        a1.q = *(const uint4*)&As[(wv * 32 + 16 + lr) * ROWP + k0 + 8 * lg];
        b0.q = *(const uint4*)&Bs[(0  + lr) * ROWP + k0 + 8 * lg];
        b1.q = *(const uint4*)&Bs[(16 + lr) * ROWP + k0 + 8 * lg];
        b2.q = *(const uint4*)&Bs[(32 + lr) * ROWP + k0 + 8 * lg];
        b3.q = *(const uint4*)&Bs[(48 + lr) * ROWP + k0 + 8 * lg];
        acc[0][0] = __builtin_amdgcn_mfma_f32_16x16x32_bf16(a0.v, b0.v, acc[0][0], 0, 0, 0);
        acc[0][1] = __builtin_amdgcn_mfma_f32_16x16x32_bf16(a0.v, b1.v, acc[0][1], 0, 0, 0);
        acc[0][2] = __builtin_amdgcn_mfma_f32_16x16x32_bf16(a0.v, b2.v, acc[0][2], 0, 0, 0);
        acc[0][3] = __builtin_amdgcn_mfma_f32_16x16x32_bf16(a0.v, b3.v, acc[0][3], 0, 0, 0);
        acc[1][0] = __builtin_amdgcn_mfma_f32_16x16x32_bf16(a1.v, b0.v, acc[1][0], 0, 0, 0);
        acc[1][1] = __builtin_amdgcn_mfma_f32_16x16x32_bf16(a1.v, b1.v, acc[1][1], 0, 0, 0);
        acc[1][2] = __builtin_amdgcn_mfma_f32_16x16x32_bf16(a1.v, b2.v, acc[1][2], 0, 0, 0);
        acc[1][3] = __builtin_amdgcn_mfma_f32_16x16x32_bf16(a1.v, b3.v, acc[1][3], 0, 0, 0);
    }
    // D[row = wv*32+fr*16+4*lg+r][col = fc*16+lr] ; b1 folded into cols 32..63; fp8 store
    float badd[4];
    badd[0] = 0.f; badd[1] = 0.f; badd[2] = b1v[lr]; badd[3] = b1v[16 + lr];
#pragma unroll
    for (int fr = 0; fr < 2; ++fr)
#pragma unroll
        for (int fc = 0; fc < 4; ++fc)
#pragma unroll
            for (int r = 0; r < 4; ++r) {
                int gm = m0 + wv * 32 + fr * 16 + 4 * lg + r;
                if (gm < N_NODES)
                    nb[(size_t)gm * NAB + fc * 16 + lr] = f2fp8(acc[fr][fc][r] + badd[fc]);
            }
}

// ---- scan (2 kernels); scan1 adds +1 per node for the self-loop ----
__global__ __launch_bounds__(1024) void k_scan1(const int* __restrict__ deg,
                                                int* __restrict__ rowptr,
                                                int* __restrict__ bsum) {
    __shared__ int sd[1024];
    int tid = threadIdx.x;
    int i = blockIdx.x * 1024 + tid;
    int v = (i < N_NODES) ? deg[i] + 1 : 0;
    sd[tid] = v;
    __syncthreads();
    for (int off = 1; off < 1024; off <<= 1) {
        int t = (tid >= off) ? sd[tid - off] : 0;
        __syncthreads();
        sd[tid] += t;
        __syncthreads();
    }
    if (i < N_NODES) rowptr[i] = sd[tid] - v;          // block-local exclusive
    if (tid == 1023) bsum[blockIdx.x] = sd[1023];
}
#define NBLK_SCAN 49
__global__ __launch_bounds__(64) void k_scan2(const int* __restrict__ bsum,
                                              int* __restrict__ boff,
                                              int* __restrict__ rowptr) {
    int l = threadIdx.x;
    int orig = (l < NBLK_SCAN) ? bsum[l] : 0;
    int v = orig;
    for (int off = 1; off < 64; off <<= 1) {
        int t = __shfl_up(v, off);
        if (l >= off) v += t;
    }
    if (l < NBLK_SCAN) boff[l] = v - orig;             // exclusive block offsets
    if (l == 63) rowptr[N_NODES] = v;                  // grand total (global)
}

// ---- fused per-edge MLP + gate + exp + CSR scatter; NO atomics; boff folded in ----
__global__ __launch_bounds__(256, 8) void k_edges(const u8* __restrict__ nb,
                                                  const int* __restrict__ ei,
                                                  const int* __restrict__ rank,
                                                  const int* __restrict__ rowptr,
                                                  const int* __restrict__ boff,
                                                  const float* __restrict__ eww,
                                                  const float* __restrict__ w2,
                                                  const float* __restrict__ b2v,
                                                  uint4* __restrict__ esb,
                                                  float* __restrict__ dslot) {
    int e = blockIdx.x * 256 + threadIdx.x;
    bool valid = e < ET_EDGES;
    int s = 0, d = 0, pos = 0;
    if (valid) {
        if (e < N_EDGES) {
            s = ei[e]; d = ei[N_EDGES + e];
            pos = rowptr[d] + boff[d >> 10] + rank[e];       // global slot, no RMW
        } else {
            s = d = e - N_EDGES;
            int v1 = d + 1;
            pos = ((v1 < N_NODES) ? rowptr[v1] + boff[v1 >> 10] : rowptr[N_NODES]) - 1;
        }
    }
    // eww loads depend only on e: issue before anything needs them
    int ee = valid ? e : 0;
    float ew[NHEADS];
#pragma unroll
    for (int t = 0; t < NHEADS; ++t) ew[t] = eww[(size_t)t * ET_EDGES + ee];

    const uint4* rp = (const uint4*)(nb + (size_t)s * NAB);   // a = bytes 0..31
    const uint4* rq = (const uint4*)(nb + (size_t)d * NAB);   // b = bytes 32..63
    uint4 Au = rp[0], Av = rp[1];
    uint4 Bu = rq[2], Bv = rq[3];

    float h[HIDDEN];
#define DEC8(au, bu, base) { \
        f32x2 al = __builtin_amdgcn_cvt_pk_f32_fp8((int)(au), false); \
        f32x2 ah = __builtin_amdgcn_cvt_pk_f32_fp8((int)(au), true);  \
        f32x2 bl = __builtin_amdgcn_cvt_pk_f32_fp8((int)(bu), false); \
        f32x2 bh = __builtin_amdgcn_cvt_pk_f32_fp8((int)(bu), true);  \
        h[base+0] = fmaxf(al.x + bl.x, 0.f); h[base+1] = fmaxf(al.y + bl.y, 0.f); \
        h[base+2] = fmaxf(ah.x + bh.x, 0.f); h[base+3] = fmaxf(ah.y + bh.y, 0.f); }
    DEC8(Au.x, Bu.x, 0)  DEC8(Au.y, Bu.y, 4)  DEC8(Au.z, Bu.z, 8)  DEC8(Au.w, Bu.w, 12)
    DEC8(Av.x, Bv.x, 16) DEC8(Av.y, Bv.y, 20) DEC8(Av.z, Bv.z, 24) DEC8(Av.w, Bv.w, 28)
#undef DEC8

    float z[NHEADS];
#pragma unroll
    for (int t = 0; t < NHEADS; ++t) z[t] = 0.f;
#pragma unroll
    for (int j = 0; j < HIDDEN; ++j)
#pragma unroll
        for (int t = 0; t < NHEADS; ++t) z[t] = fmaf(h[j], w2[j * NHEADS + t], z[t]);

    float pe[NHEADS];
#pragma unroll
    for (int t = 0; t < NHEADS; ++t) {
        float dyn = 1.f / (1.f + __expf(-(z[t] + b2v[t])));
        float tw  = ew[t] * dyn;
        tw = fmaxf(tw, 0.01f * tw);                 // leaky_relu
        pe[t] = valid ? __expf(tw) : 0.f;
    }
    if (valid) {
        uint4 q0, q1;
        q0.x = pack2bf(pe[0], pe[1]); q0.y = pack2bf(pe[2], pe[3]);
        q0.z = pack2bf(pe[4], pe[5]); q0.w = pack2bf(pe[6], pe[7]);
        q1 = make_uint4((u32)s, 0u, 0u, 0u);
        uint4* dst = esb + 2 * (size_t)pos;         // one 32B record: single line touch
        dst[0] = q0;
        dst[1] = q1;
    }
    __shared__ float blk[NHEADS];
    if (threadIdx.x < NHEADS) blk[threadIdx.x] = 0.f;
    __syncthreads();
    int lane = threadIdx.x & 63;
#pragma unroll
    for (int t = 0; t < NHEADS; ++t) {
        float v = pe[t];
        for (int off = 32; off > 0; off >>= 1) v += __shfl_xor(v, off);
        if (lane == 0) atomicAdd(&blk[t], v);
    }
    __syncthreads();
    if (threadIdx.x < NHEADS)
        atomicAdd(&dslot[(blockIdx.x & (NSLOT - 1)) * NHEADS + threadIdx.x], blk[threadIdx.x]);
}

// ---- aggregate: SGPR record loads (4-edge unroll) + v_pk_fma_f32; bf16 aggx out ----
__global__ __launch_bounds__(256, 8) void k_agg(const u16* __restrict__ xb,
                                                const uint4* __restrict__ esb,
                                                const int* __restrict__ rowptr,
                                                const int* __restrict__ boff,
                                                const float* __restrict__ dslot,
                                                u16* __restrict__ aggx) {
    int lane = threadIdx.x & 63;
    int n = __builtin_amdgcn_readfirstlane(blockIdx.x * 4 + (threadIdx.x >> 6));
    if (n >= N_NODES) return;
    f32x2 acc[8];
#pragma unroll
    for (int h = 0; h < 8; ++h) acc[h] = (f32x2){0.f, 0.f};
    int beg = __builtin_amdgcn_readfirstlane(rowptr[n] + boff[n >> 10]);
    int end;
    if (n + 1 < N_NODES) end = __builtin_amdgcn_readfirstlane(rowptr[n + 1] + boff[(n + 1) >> 10]);
    else                 end = __builtin_amdgcn_readfirstlane(rowptr[N_NODES]);
    const u32* rec = (const u32*)esb;          // uniform base; idx uniform -> s_load
    const u16* xrow = xb + 2 * lane;

#define WACC(w0u, w1u, w2u, w3u, xv) { \
        acc[0] = __builtin_elementwise_fma((f32x2){bfl(w0u), bfl(w0u)}, xv, acc[0]); \
        acc[1] = __builtin_elementwise_fma((f32x2){bfh(w0u), bfh(w0u)}, xv, acc[1]); \
        acc[2] = __builtin_elementwise_fma((f32x2){bfl(w1u), bfl(w1u)}, xv, acc[2]); \
        acc[3] = __builtin_elementwise_fma((f32x2){bfh(w1u), bfh(w1u)}, xv, acc[3]); \
        acc[4] = __builtin_elementwise_fma((f32x2){bfl(w2u), bfl(w2u)}, xv, acc[4]); \
        acc[5] = __builtin_elementwise_fma((f32x2){bfh(w2u), bfh(w2u)}, xv, acc[5]); \
        acc[6] = __builtin_elementwise_fma((f32x2){bfl(w3u), bfl(w3u)}, xv, acc[6]); \
        acc[7] = __builtin_elementwise_fma((f32x2){bfh(w3u), bfh(w3u)}, xv, acc[7]); }

    int idx = beg;
    for (; idx + 4 <= end; idx += 4) {
        size_t r = (size_t)idx * 8;            // u32 index of record; 4 records = 128 B scalar
        u32 a0 = rec[r + 0],  a1 = rec[r + 1],  a2 = rec[r + 2],  a3 = rec[r + 3];
        int  s0 = (int)rec[r + 4];
        u32 b0 = rec[r + 8],  b1 = rec[r + 9],  b2 = rec[r + 10], b3 = rec[r + 11];
        int  s1 = (int)rec[r + 12];
        u32 c0 = rec[r + 16], c1 = rec[r + 17], c2 = rec[r + 18], c3 = rec[r + 19];
        int  s2 = (int)rec[r + 20];
        u32 d0 = rec[r + 24], d1 = rec[r + 25], d2 = rec[r + 26], d3 = rec[r + 27];
        int  s3 = (int)rec[r + 28];
        u32 xu0 = *(const u32*)(xrow + (size_t)s0 * NFEAT);
        u32 xu1 = *(const u32*)(xrow + (size_t)s1 * NFEAT);
        u32 xu2 = *(const u32*)(xrow + (size_t)s2 * NFEAT);
        u32 xu3 = *(const u32*)(xrow + (size_t)s3 * NFEAT);
        f32x2 xv0 = {bfl(xu0), bfh(xu0)};
        f32x2 xv1 = {bfl(xu1), bfh(xu1)};
        f32x2 xv2 = {bfl(xu2), bfh(xu2)};
        f32x2 xv3 = {bfl(xu3), bfh(xu3)};
        WACC(a0, a1, a2, a3, xv0)
        WACC(b0, b1, b2, b3, xv1)
        WACC(c0, c1, c2, c3, xv2)
        WACC(d0, d1, d2, d3, xv3)
    }
    for (; idx < end; ++idx) {
        size_t r = (size_t)idx * 8;
        u32 a0 = rec[r + 0], a1 = rec[r + 1], a2 = rec[r + 2], a3 = rec[r + 3];
        int  s0 = (int)rec[r + 4];
        u32 xu0 = *(const u32*)(xrow + (size_t)s0 * NFEAT);
        f32x2 xv0 = {bfl(xu0), bfh(xu0)};
        WACC(a0, a1, a2, a3, xv0)
    }
#undef WACC
    // epilogue: wave-parallel denom reduce over 64 slots (lane = slot); regs free here
    float4 da = *(const float4*)(dslot + lane * NHEADS);
    float4 db = *(const float4*)(dslot + lane * NHEADS + 4);
#pragma unroll
    for (int off = 32; off > 0; off >>= 1) {
        da.x += __shfl_xor(da.x, off); da.y += __shfl_xor(da.y, off);
        da.z += __shfl_xor(da.z, off); da.w += __shfl_xor(da.w, off);
        db.x += __shfl_xor(db.x, off); db.y += __shfl_xor(db.y, off);
        db.z += __shfl_xor(db.z, off); db.w += __shfl_xor(db.w, off);
    }
    u16* dst = aggx + (size_t)n * KAGG + 2 * lane;
    *(u32*)(dst + 0 * NFEAT) = pack2bf(acc[0][0] / da.x, acc[0][1] / da.x);
    *(u32*)(dst + 1 * NFEAT) = pack2bf(acc[1][0] / da.y, acc[1][1] / da.y);
    *(u32*)(dst + 2 * NFEAT) = pack2bf(acc[2][0] / da.z, acc[2][1] / da.z);
    *(u32*)(dst + 3 * NFEAT) = pack2bf(acc[3][0] / da.w, acc[3][1] / da.w);
    *(u32*)(dst + 4 * NFEAT) = pack2bf(acc[4][0] / db.x, acc[4][1] / db.x);
    *(u32*)(dst + 5 * NFEAT) = pack2bf(acc[5][0] / db.y, acc[5][1] / db.y);
    *(u32*)(dst + 6 * NFEAT) = pack2bf(acc[6][0] / db.z, acc[6][1] / db.z);
    *(u32*)(dst + 7 * NFEAT) = pack2bf(acc[7][0] / db.w, acc[7][1] / db.w);
}

// ---- GEMM2 + bias + LayerNorm: out[N][64] = LN(aggx[N][1024] @ pwT^T + proj_b) ----
__global__ __launch_bounds__(256) void k_out(const u16* __restrict__ aggx,
                                             const u16* __restrict__ pwT,
                                             const float* __restrict__ proj_b,
                                             const float* __restrict__ ln_g,
                                             const float* __restrict__ ln_b,
                                             float* __restrict__ out) {
    __shared__ __align__(16) u16 As[128 * ROWP];
    __shared__ __align__(16) u16 Bs[64 * ROWP];
    int tid = threadIdx.x;
    int m0 = blockIdx.x * 128;
    int wv = tid >> 6, l = tid & 63, lr = l & 15, lg = l >> 4;
    union FR { uint4 q; bf16x8 v; };
    f32x4 acc[2][4];
#pragma unroll
    for (int fr = 0; fr < 2; ++fr)
#pragma unroll
        for (int fc = 0; fc < 4; ++fc) acc[fr][fc] = (f32x4){0.f, 0.f, 0.f, 0.f};

    for (int kt = 0; kt < 8; ++kt) {
        int kb = kt * 128;
        __syncthreads();
#pragma unroll
        for (int p = 0; p < 8; ++p) {
            int idx = tid + p * 256;
            int row = idx >> 4, fo = idx & 15;
            int gm = m0 + row;
            uint4 v = make_uint4(0u, 0u, 0u, 0u);
            if (gm < N_NODES) v = *(const uint4*)(aggx + (size_t)gm * KAGG + kb + fo * 8);
            *(uint4*)&As[row * ROWP + fo * 8] = v;
        }
#pragma unroll
        for (int p = 0; p < 4; ++p) {
            int idx = tid + p * 256;
            int col = idx >> 4, fo = idx & 15;
            *(uint4*)&Bs[col * ROWP + fo * 8] =
                *(const uint4*)(pwT + (size_t)col * KAGG + kb + fo * 8);
        }
        __syncthreads();
#pragma unroll
        for (int ks = 0; ks < 4; ++ks) {
            int k0 = ks * 32;
            FR a0, a1, b0, b1, b2, b3;
            a0.q = *(const uint4*)&As[(wv * 32 + 0  + lr) * ROWP + k0 + 8 * lg];
            a1.q = *(const uint4*)&As[(wv * 32 + 16 + lr) * ROWP + k0 + 8 * lg];
            b0.q = *(const uint4*)&Bs[(0  + lr) * ROWP + k0 + 8 * lg];
            b1.q = *(const uint4*)&Bs[(16 + lr) * ROWP + k0 + 8 * lg];
            b2.q = *(const uint4*)&Bs[(32 + lr) * ROWP + k0 + 8 * lg];
            b3.q = *(const uint4*)&Bs[(48 + lr) * ROWP + k0 + 8 * lg];
            acc[0][0] = __builtin_amdgcn_mfma_f32_16x16x32_bf16(a0.v, b0.v, acc[0][0], 0, 0, 0);
            acc[0][1] = __builtin_amdgcn_mfma_f32_16x16x32_bf16(a0.v, b1.v, acc[0][1], 0, 0, 0);
            acc[0][2] = __builtin_amdgcn_mfma_f32_16x16x32_bf16(a0.v, b2.v, acc[0][2], 0, 0, 0);
            acc[0][3] = __builtin_amdgcn_mfma_f32_16x16x32_bf16(a0.v, b3.v, acc[0][3], 0, 0, 0);
            acc[1][0] = __builtin_amdgcn_mfma_f32_16x16x32_bf16(a1.v, b0.v, acc[1][0], 0, 0, 0);
            acc[1][1] = __builtin_amdgcn_mfma_f32_16x16x32_bf16(a1.v, b1.v, acc[1][1], 0, 0, 0);
            acc[1][2] = __builtin_amdgcn_mfma_f32_16x16x32_bf16(a1.v, b2.v, acc[1][2], 0, 0, 0);
            acc[1][3] = __builtin_amdgcn_mfma_f32_16x16x32_bf16(a1.v, b3.v, acc[1][3], 0, 0, 0);
        }
    }
    float pb4[4], g4[4], b4[4];
#pragma unroll
    for (int fc = 0; fc < 4; ++fc) {
        pb4[fc] = proj_b[fc * 16 + lr];
        g4[fc]  = ln_g[fc * 16 + lr];
        b4[fc]  = ln_b[fc * 16 + lr];
    }
#pragma unroll
    for (int fr = 0; fr < 2; ++fr)
#pragma unroll
        for (int r = 0; r < 4; ++r) {
            int gm = m0 + wv * 32 + fr * 16 + 4 * lg + r;
            float v[4];
#pragma unroll
            for (int fc = 0; fc < 4; ++fc) v[fc] = acc[fr][fc][r] + pb4[fc];
            float s = v[0] + v[1] + v[2] + v[3];
            s += __shfl_xor(s, 1); s += __shfl_xor(s, 2);
            s += __shfl_xor(s, 4); s += __shfl_xor(s, 8);
            float mu = s * (1.f / 64.f);
            float q = 0.f;
#pragma unroll
            for (int fc = 0; fc < 4; ++fc) { v[fc] -= mu; q = fmaf(v[fc], v[fc], q); }
            q += __shfl_xor(q, 1); q += __shfl_xor(q, 2);
            q += __shfl_xor(q, 4); q += __shfl_xor(q, 8);
            float inv = rsqrtf(q * (1.f / 64.f) + 1e-5f);
            if (gm < N_NODES) {
#pragma unroll
                for (int fc = 0; fc < 4; ++fc)
                    out[(size_t)gm * NCLASS + fc * 16 + lr] = v[fc] * inv * g4[fc] + b4[fc];
            }
        }
}

extern "C" void kernel_launch(void* const* d_in, const int* in_sizes, int n_in,
                              void* d_out, int out_size, void* d_ws, size_t ws_size,
                              hipStream_t stream) {
    const float* x      = (const float*)d_in[0];
    const int*   ei     = (const int*)  d_in[1];
    const float* eww    = (const float*)d_in[2];
    const float* w1     = (const float*)d_in[3];
    const float* b1v    = (const float*)d_in[4];
    const float* w2     = (const float*)d_in[5];
    const float* b2v    = (const float*)d_in[6];
    const float* proj_w = (const float*)d_in[7];
    const float* proj_b = (const float*)d_in[8];
    const float* ln_g   = (const float*)d_in[9];
    const float* ln_b   = (const float*)d_in[10];
    float* out = (float*)d_out;

    char* ws = (char*)d_ws;
    size_t off = 0;
    auto alloc = [&](size_t bytes) -> void* {
        void* p = ws + off;
        off = (off + bytes + 255) & ~(size_t)255;
        return p;
    };
    u16*   aggx   = (u16*)  alloc((size_t)N_NODES * KAGG * 2);    // 102.4 MB
    u8*    nb     = (u8*)   alloc((size_t)N_NODES * NAB);         // 3.2 MB (fp8)
    u16*   xb     = (u16*)  alloc((size_t)N_NODES * NFEAT * 2);   // 12.8 MB
    u16*   WpT    = (u16*)  alloc((size_t)NAB * NFEAT * 2);       // 16 KB
    u16*   pwT    = (u16*)  alloc((size_t)NCLASS * KAGG * 2);     // 128 KB
    uint4* esb    = (uint4*)alloc((size_t)ET_EDGES * 32);         // 27.2 MB
    int*   rank   = (int*)  alloc((size_t)N_EDGES * 4);           // 3.2 MB
    // deg + dslot adjacent: one memset covers both
    int*   deg    = (int*)  alloc((size_t)N_NODES * 4);           // 200000 B -> 200192 aligned
    float* dslot  = (float*)alloc(NSLOT * NHEADS * 4);            // 2 KB
    int*   rowptr = (int*)  alloc((size_t)(N_NODES + 1) * 4);
    int*   bsum   = (int*)  alloc(64 * 4);
    int*   boff   = (int*)  alloc(64 * 4);
    if (off > ws_size) return;

    size_t deg_pad = (((size_t)N_NODES * 4 + 255) & ~(size_t)255);
    hipMemsetAsync(deg, 0, deg_pad + NSLOT * NHEADS * 4, stream);  // deg + dslot in one call

    k_prep<<<288 + (N_EDGES + 255) / 256, 256, 0, stream>>>(w1, proj_w, ei, WpT, pwT, deg, rank);
    k_scan1<<<NBLK_SCAN, 1024, 0, stream>>>(deg, rowptr, bsum);
    k_scan2<<<1, 64, 0, stream>>>(bsum, boff, rowptr);

    k_gemm<<<(N_NODES + 127) / 128, 256, 0, stream>>>(x, WpT, b1v, nb, xb);

    k_edges<<<(ET_EDGES + 255) / 256, 256, 0, stream>>>(nb, ei, rank, rowptr, boff, eww, w2, b2v,
                                                        esb, dslot);
    k_agg<<<(N_NODES + 3) / 4, 256, 0, stream>>>(xb, esb, rowptr, boff, dslot, aggx);
    k_out<<<(N_NODES + 127) / 128, 256, 0, stream>>>(aggx, pwT, proj_b, ln_g, ln_b, out);
}